// Round 7
// baseline (181.148 us; speedup 1.0000x reference)
//
#include <hip/hip_runtime.h>
#include <stdint.h>

typedef unsigned long long u64;
typedef __attribute__((ext_vector_type(4))) float floatx4;
typedef __attribute__((ext_vector_type(2))) long longx2;

#define CDIM   256
#define KCODES 1024

__device__ __forceinline__ void gload16(const void* g, void* l) {
    __builtin_amdgcn_global_load_lds((const __attribute__((address_space(1))) void*)g,
                                     (__attribute__((address_space(3))) void*)l, 16, 0, 0);
}
__device__ __forceinline__ unsigned pk4_fp8(float a, float b, float c, float d) {
    int u = __builtin_amdgcn_cvt_pk_fp8_f32(a, b, 0, false);
    u = __builtin_amdgcn_cvt_pk_fp8_f32(c, d, u, true);
    return (unsigned)u;
}

// ---------------- emb -> emb8 [k][256B] fp8(256*e), K-permuted; e_sqs = 4096*e_sq
__global__ void emb_prep(const float* __restrict__ emb, unsigned char* __restrict__ emb8,
                         float* __restrict__ e_sqs) {
    int k = blockIdx.x, l = threadIdx.x;            // 64 lanes
    float4 v = ((const float4*)(emb + (size_t)k * CDIM))[l];
    float s = v.x * v.x + v.y * v.y + v.z * v.z + v.w * v.w;
    int c = l * 4;
    int kt = c >> 6, cl = c & 63;
    int ks = cl >> 5, q = (cl & 31) >> 3, j0 = cl & 7;
    unsigned pk = pk4_fp8(v.x * 256.f, v.y * 256.f, v.z * 256.f, v.w * 256.f);
    *(unsigned*)(emb8 + (size_t)k * 256 + kt * 64 + q * 16 + ks * 8 + j0) = pk;
#pragma unroll
    for (int off = 32; off >= 1; off >>= 1) s += __shfl_down(s, off, 64);
    if (l == 0) e_sqs[k] = 4096.f * s;
}

// ---------------- fused VQ: B-resident LDS, barrier-free K-loop, A in registers
// grid 256 (1 block/CU), block 256 threads; block = 256 consecutive positions
__global__ __launch_bounds__(256, 1)
void vq_fused(const float* __restrict__ z, const float* __restrict__ emb,
              const unsigned char* __restrict__ emb8, const float* __restrict__ e_sqs,
              float* __restrict__ out, float* __restrict__ loss)
{
    __shared__ __align__(16) char smem[153600];
    unsigned char* Bs = (unsigned char*)smem;             // 128 KB: 512 codes x 256 B
    unsigned char* As = (unsigned char*)(smem + 131072);  // 16 KB: 64 pos x 256 B (per tile)
    float*    z2p  = (float*)(smem + 147456);             // 256 f
    float*    z2   = (float*)(smem + 148480);             // 256 f
    unsigned* runsh = (unsigned*)(smem + 149504);         // 256 x 2 u32
    unsigned* sidx  = (unsigned*)(smem + 151552);         // 256 u32
    float*    dsh  = (float*)(smem + 152576);             // 256 f
    float*    smG  = (float*)smem;                        // gather overlay (64 x 260 f)

    const int tid = threadIdx.x;
    const int wave = tid >> 6, lane = tid & 63;
    const int mh = wave & 1, nh = wave >> 1;              // pos-half, code-half
    const int q = lane >> 4, r = lane & 15;
    const int b = blockIdx.x >> 2, s0 = (blockIdx.x & 3) << 8;

    // ---- issue B half-0 staging (codes 0..511); drained by phase-0 barriers ----
    {
        const int grow = lane >> 4, glin = lane & 15;
#pragma unroll
        for (int i = 0; i < 32; ++i) {
            const int row = i * 16 + wave * 4 + grow;
            const int gs = (glin & 8) | ((glin & 7) ^ (row & 7));
            gload16(emb8 + (size_t)row * 256 + gs * 16, Bs + (size_t)row * 256 + glin * 16);
        }
    }

    // ---- phase 0: per 64-pos tile: z load + z_sq + fp8 convert -> As; owner waves grab fa ----
    longx2 fa[8][4];
    {
        const int p = tid & 63, cg = tid >> 6;
#pragma unroll
        for (int t = 0; t < 4; ++t) {
            const float* zb = z + ((size_t)(b * 256 + cg * 64)) * 1024 + s0 + t * 64 + p;
            float ps = 0.f;
#pragma unroll
            for (int qq = 0; qq < 4; ++qq)
#pragma unroll
                for (int ks = 0; ks < 2; ++ks) {
                    float v[8];
#pragma unroll
                    for (int j = 0; j < 8; ++j) {
                        v[j] = zb[(size_t)(ks * 32 + qq * 8 + j) * 1024];
                        ps = fmaf(v[j], v[j], ps);
                    }
                    uint2 w;
                    w.x = pk4_fp8(16.f * v[0], 16.f * v[1], 16.f * v[2], 16.f * v[3]);
                    w.y = pk4_fp8(16.f * v[4], 16.f * v[5], 16.f * v[6], 16.f * v[7]);
                    const int pgl = cg * 4 + qq;
                    const int pgs = (pgl & 8) | ((pgl & 7) ^ (p & 7));
                    *(uint2*)(As + p * 256 + pgs * 16 + ks * 8) = w;
                }
            z2p[cg * 64 + p] = ps;
            __syncthreads();
            if (tid < 64)
                z2[t * 64 + tid] = (z2p[tid] + z2p[64 + tid]) + (z2p[128 + tid] + z2p[192 + tid]);
            if (mh == (t >> 1)) {                        // owner waves load A fragments
#pragma unroll
                for (int mtl = 0; mtl < 4; ++mtl) {
                    const int prow = mtl * 16 + r;
#pragma unroll
                    for (int kt = 0; kt < 4; ++kt) {
                        const int pgl = kt * 4 + q;
                        const int pgs = (pgl & 8) | ((pgl & 7) ^ (prow & 7));
                        fa[(t & 1) * 4 + mtl][kt] = *(const longx2*)(As + prow * 256 + pgs * 16);
                    }
                }
            }
            __syncthreads();
        }
    }

    // ---- K-loop: 2 resident halves x 4 code-groups, NO barriers inside ----
    floatx4 acc[8][4] = {};
    unsigned run[32];
#pragma unroll
    for (int j = 0; j < 32; ++j) run[j] = 0xFFFFFFFFu;

    for (int h = 0; h < 2; ++h) {
        if (h == 1) {
            __syncthreads();                             // all waves done with half 0
            const int grow = lane >> 4, glin = lane & 15;
#pragma unroll
            for (int i = 0; i < 32; ++i) {
                const int row = i * 16 + wave * 4 + grow;
                const int gs = (glin & 8) | ((glin & 7) ^ (row & 7));
                gload16(emb8 + (size_t)(512 + row) * 256 + gs * 16,
                        Bs + (size_t)row * 256 + glin * 16);
            }
            __syncthreads();                             // drain staging
        }
        for (int ng = 0; ng < 4; ++ng) {
            const int cb = nh * 256 + ng * 64;
            longx2 fb[4][4];
#pragma unroll
            for (int nt = 0; nt < 4; ++nt)
#pragma unroll
                for (int kt = 0; kt < 4; ++kt) {
                    const int row = cb + nt * 16 + r;
                    const int pgl = kt * 4 + q;
                    const int gs = (pgl & 8) | ((pgl & 7) ^ (r & 7));
                    fb[nt][kt] = *(const longx2*)(Bs + (size_t)row * 256 + gs * 16);
                }
#pragma unroll
            for (int kt = 0; kt < 4; ++kt)
#pragma unroll
                for (int ks = 0; ks < 2; ++ks)
#pragma unroll
                    for (int mt = 0; mt < 8; ++mt)
#pragma unroll
                        for (int nt = 0; nt < 4; ++nt)
                            acc[mt][nt] = __builtin_amdgcn_mfma_f32_16x16x32_fp8_fp8(
                                fa[mt][kt][ks], fb[nt][kt][ks], acc[mt][nt], 0, 0, 0);
            // fold into running argmin; val = 16384 + 4096 e_sq - 2 dot~ > 0
            const int gb = h * 512 + cb;
            float ev[4];
#pragma unroll
            for (int nt = 0; nt < 4; ++nt) ev[nt] = e_sqs[gb + nt * 16 + r] + 16384.f;
#pragma unroll
            for (int mt = 0; mt < 8; ++mt) {
#pragma unroll
                for (int reg = 0; reg < 4; ++reg) {
                    float mv = 3e7f; int mk = 0;
#pragma unroll
                    for (int nt = 0; nt < 4; ++nt) {
                        float v = ev[nt] - 2.f * acc[mt][nt][reg];
                        if (v < mv) { mv = v; mk = gb + nt * 16 + r; }
                    }
                    unsigned pk = ((unsigned)(mv * 32.f) << 10) | (unsigned)mk;
                    run[mt * 4 + reg] = min(run[mt * 4 + reg], pk);
                }
#pragma unroll
                for (int nt = 0; nt < 4; ++nt) acc[mt][nt] = (floatx4){0.f, 0.f, 0.f, 0.f};
            }
        }
    }

    // ---- argmin merge: lanes (r) -> LDS (nh) -> final per position ----
#pragma unroll
    for (int j = 0; j < 32; ++j) {
        unsigned pk = run[j];
#pragma unroll
        for (int off = 1; off < 16; off <<= 1)
            pk = min(pk, (unsigned)__shfl_xor((int)pk, off, 64));
        if (r == 0)
            runsh[(mh * 128 + (j >> 2) * 16 + q * 4 + (j & 3)) * 2 + nh] = pk;
    }
    __syncthreads();
    {
        unsigned m = min(runsh[tid * 2], runsh[tid * 2 + 1]);
        sidx[tid] = m & 1023u;
        dsh[tid] = z2[tid] + ((float)(m >> 10) * (1.f / 32.f) - 16384.f) * (1.f / 4096.f);
    }
    __syncthreads();
    if (tid < 64) {
        float s = (dsh[tid] + dsh[64 + tid]) + (dsh[128 + tid] + dsh[192 + tid]);
#pragma unroll
        for (int off = 32; off >= 1; off >>= 1) s += __shfl_down(s, off, 64);
        if (tid == 0) atomicAdd(loss, s * (1.25f / 16777216.f));
    }
    __syncthreads();                                     // Bs dead -> smG reuse

    // ---- gather + coalesced write: 4 chunks of 64 positions ----
    for (int chunk = 0; chunk < 4; ++chunk) {
        const int rbase = chunk * 64;
#pragma unroll
        for (int i = 0; i < 16; ++i) {
            const int row = rbase + wave * 16 + i;       // wave-uniform
            gload16(emb + (size_t)sidx[row] * CDIM + lane * 4,
                    smG + (size_t)(row - rbase) * 260 + lane * 4);
        }
        __syncthreads();
        {
            const int s = tid & 63, cq = tid >> 6;
            float* ob = out + ((size_t)(b * 256 + cq * 64)) * 1024 + s0 + rbase + s;
#pragma unroll
            for (int c4 = 0; c4 < 16; ++c4) {
                float4 v = *(const float4*)(smG + s * 260 + cq * 64 + c4 * 4);
                ob[(size_t)(c4 * 4 + 0) * 1024] = v.x;
                ob[(size_t)(c4 * 4 + 1) * 1024] = v.y;
                ob[(size_t)(c4 * 4 + 2) * 1024] = v.z;
                ob[(size_t)(c4 * 4 + 3) * 1024] = v.w;
            }
        }
        __syncthreads();
    }
}

extern "C" void kernel_launch(void* const* d_in, const int* in_sizes, int n_in,
                              void* d_out, int out_size, void* d_ws, size_t ws_size,
                              hipStream_t stream)
{
    const float* z   = (const float*)d_in[0];
    const float* emb = (const float*)d_in[1];
    float* out = (float*)d_out;

    unsigned char* emb8 = (unsigned char*)d_ws;           // 256 KB
    float* e_sqs = (float*)((char*)d_ws + 262144);        // 4 KB
    float* loss  = out + 16777216;

    hipMemsetAsync(loss, 0, sizeof(float), stream);
    emb_prep<<<KCODES, 64, 0, stream>>>(emb, emb8, e_sqs);
    vq_fused<<<256, 256, 0, stream>>>(z, emb, emb8, e_sqs, out, loss);
}

// Round 8
// 180.283 us; speedup vs baseline: 1.0048x; 1.0048x over previous
//
#include <hip/hip_runtime.h>
#include <stdint.h>

typedef __attribute__((ext_vector_type(4))) float floatx4;
typedef __attribute__((ext_vector_type(2))) long longx2;

#define CDIM   256
#define KCODES 1024

__device__ __forceinline__ unsigned pk4_fp8(float a, float b, float c, float d) {
    int u = __builtin_amdgcn_cvt_pk_fp8_f32(a, b, 0, false);
    u = __builtin_amdgcn_cvt_pk_fp8_f32(c, d, u, true);
    return (unsigned)u;
}

// ---------------- emb -> emb8 [k][256B] fp8(256*e), K-permuted (plain granules); e_sqs = 4096*e_sq
__global__ void emb_prep(const float* __restrict__ emb, unsigned char* __restrict__ emb8,
                         float* __restrict__ e_sqs) {
    int k = blockIdx.x, l = threadIdx.x;            // 64 lanes
    float4 v = ((const float4*)(emb + (size_t)k * CDIM))[l];
    float s = v.x * v.x + v.y * v.y + v.z * v.z + v.w * v.w;
    int c = l * 4;
    int kt = c >> 6, cl = c & 63;
    int ks = cl >> 5, q = (cl & 31) >> 3, j0 = cl & 7;
    unsigned pk = pk4_fp8(v.x * 256.f, v.y * 256.f, v.z * 256.f, v.w * 256.f);
    *(unsigned*)(emb8 + (size_t)k * 256 + kt * 64 + q * 16 + ks * 8 + j0) = pk;
#pragma unroll
    for (int off = 32; off >= 1; off >>= 1) s += __shfl_down(s, off, 64);
    if (l == 0) e_sqs[k] = 4096.f * s;
}

// ---------------- GEMM+argmin: A-frags persistent in regs, B from L2, no K-loop barriers
// grid 1024 x 256 thr; block = 64 positions, all 1024 codes
// wave(mh,nh): mh -> 32-pos half, nh -> 512-code half
__global__ __launch_bounds__(256, 3)
void vq_gemm(const float* __restrict__ z, const unsigned char* __restrict__ emb8,
             const float* __restrict__ e_sqs, unsigned* __restrict__ sidx_g,
             float* __restrict__ loss)
{
    __shared__ __align__(16) char smem[18432];
    unsigned char* As = (unsigned char*)smem;        // 16 KB: 64 pos x 256 B, swizzled
    float*    z2p = (float*)(smem + 16384);          // 256 f
    float*    z2  = (float*)(smem + 17408);          // 64 f
    unsigned* red = (unsigned*)(smem + 17664);       // 64 x 2 u32

    const int tid = threadIdx.x;
    const int wave = tid >> 6, lane = tid & 63;
    const int mh = wave & 1, nh = wave >> 1;
    const int q = lane >> 4, r = lane & 15;
    const int m0 = blockIdx.x << 6;
    const int b = m0 >> 10, s0 = m0 & 1023;

    // ---- phase 0: z load (coalesced), z_sq partial, fp8 convert -> As (swizzled) ----
    {
        const int p = tid & 63, cg = tid >> 6;
        const float* zb = z + ((size_t)(b * 256 + cg * 64)) * 1024 + s0 + p;
        float ps = 0.f;
#pragma unroll
        for (int qq = 0; qq < 4; ++qq)
#pragma unroll
            for (int ks = 0; ks < 2; ++ks) {
                float v[8];
#pragma unroll
                for (int j = 0; j < 8; ++j) {
                    v[j] = zb[(size_t)(ks * 32 + qq * 8 + j) * 1024];
                    ps = fmaf(v[j], v[j], ps);
                }
                uint2 w;
                w.x = pk4_fp8(16.f * v[0], 16.f * v[1], 16.f * v[2], 16.f * v[3]);
                w.y = pk4_fp8(16.f * v[4], 16.f * v[5], 16.f * v[6], 16.f * v[7]);
                const int pgl = cg * 4 + qq;
                const int pgs = (pgl & 8) | ((pgl & 7) ^ (p & 7));
                *(uint2*)(As + p * 256 + pgs * 16 + ks * 8) = w;
            }
        z2p[cg * 64 + p] = ps;
    }
    __syncthreads();
    if (tid < 64)
        z2[tid] = (z2p[tid] + z2p[64 + tid]) + (z2p[128 + tid] + z2p[192 + tid]);

    // ---- load persistent A fragments: 32 VGPRs, once ----
    longx2 fa[2][4];
#pragma unroll
    for (int mt = 0; mt < 2; ++mt) {
        const int row = mh * 32 + mt * 16 + r;
#pragma unroll
        for (int kt = 0; kt < 4; ++kt) {
            const int pgl = kt * 4 + q;
            const int pgs = (pgl & 8) | ((pgl & 7) ^ (row & 7));
            fa[mt][kt] = *(const longx2*)(As + row * 256 + pgs * 16);
        }
    }

    // ---- K-loop: 8 code-groups of 64, B from L2, NO barriers ----
    unsigned run[8];
#pragma unroll
    for (int j = 0; j < 8; ++j) run[j] = 0xFFFFFFFFu;

    for (int cc = 0; cc < 8; ++cc) {
        const int cb = (nh << 9) + (cc << 6);
        longx2 fb[4][4];
#pragma unroll
        for (int nt = 0; nt < 4; ++nt)
#pragma unroll
            for (int kt = 0; kt < 4; ++kt)
                fb[nt][kt] = *(const longx2*)(emb8 + (size_t)(cb + nt * 16 + r) * 256
                                              + (kt * 4 + q) * 16);
        float ev[4];
#pragma unroll
        for (int nt = 0; nt < 4; ++nt) ev[nt] = e_sqs[cb + nt * 16 + r] + 16384.f;

        floatx4 acc[2][4] = {};
#pragma unroll
        for (int kt = 0; kt < 4; ++kt)
#pragma unroll
            for (int ks = 0; ks < 2; ++ks)
#pragma unroll
                for (int mt = 0; mt < 2; ++mt)
#pragma unroll
                    for (int nt = 0; nt < 4; ++nt)
                        acc[mt][nt] = __builtin_amdgcn_mfma_f32_16x16x32_fp8_fp8(
                            fa[mt][kt][ks], fb[nt][kt][ks], acc[mt][nt], 0, 0, 0);
        // fold: val = 16384 + 4096 e_sq - 2 dot~ > 0; pack (val*32)<<10 | k
#pragma unroll
        for (int mt = 0; mt < 2; ++mt)
#pragma unroll
            for (int reg = 0; reg < 4; ++reg) {
                float mv = 3e7f; int mk = 0;
#pragma unroll
                for (int nt = 0; nt < 4; ++nt) {
                    float v = ev[nt] - 2.f * acc[mt][nt][reg];
                    if (v < mv) { mv = v; mk = cb + nt * 16 + r; }
                }
                unsigned pk = ((unsigned)(mv * 32.f) << 10) | (unsigned)mk;
                run[mt * 4 + reg] = min(run[mt * 4 + reg], pk);
            }
    }

    // ---- merge: shuffle over r, LDS over nh ----
#pragma unroll
    for (int j = 0; j < 8; ++j) {
        unsigned pk = run[j];
#pragma unroll
        for (int off = 1; off < 16; off <<= 1)
            pk = min(pk, (unsigned)__shfl_xor((int)pk, off, 64));
        if (r == 0)
            red[(mh * 32 + (j >> 2) * 16 + q * 4 + (j & 3)) * 2 + nh] = pk;
    }
    __syncthreads();
    if (tid < 64) {
        unsigned m = min(red[tid * 2], red[tid * 2 + 1]);
        sidx_g[m0 + tid] = m & 1023u;
        float d = z2[tid] + ((float)(m >> 10) * (1.f / 32.f) - 16384.f) * (1.f / 4096.f);
#pragma unroll
        for (int off = 32; off >= 1; off >>= 1) d += __shfl_down(d, off, 64);
        if (tid == 0) atomicAdd(loss, d * (1.25f / 16777216.f));
    }
}

// ---------------- gather: one block per (b,h), coalesced emb stage + coalesced out write
__global__ __launch_bounds__(256)
void vq_gather(const float* __restrict__ emb, const unsigned* __restrict__ sidx_g,
               float* __restrict__ out)
{
    __shared__ float sm[32][260];
    __shared__ unsigned sidx[32];
    const int t = threadIdx.x;
    const int bh = blockIdx.x;                 // 2048 = b*32 + h
    const int b = bh >> 5, h = bh & 31;
    const int pos0 = bh << 5;

    if (t < 32) sidx[t] = sidx_g[pos0 + t];
    __syncthreads();
    {
        const int w = t >> 3, f8 = t & 7;
        const float4* er = (const float4*)(emb + (size_t)sidx[w] * CDIM);
#pragma unroll
        for (int j = 0; j < 8; ++j) {
            float4 v = er[f8 + j * 8];
            *(float4*)&sm[w][(f8 + j * 8) * 4] = v;
        }
    }
    __syncthreads();
    const int w2 = t & 31, cg = t >> 5;        // 8 c-groups of 32
    float* ob = out + (size_t)b * 262144 + (size_t)cg * 32768 + h * 32 + w2;
#pragma unroll
    for (int cc = 0; cc < 32; ++cc)
        ob[(size_t)cc * 1024] = sm[w2][(cg << 5) + cc];
}

extern "C" void kernel_launch(void* const* d_in, const int* in_sizes, int n_in,
                              void* d_out, int out_size, void* d_ws, size_t ws_size,
                              hipStream_t stream)
{
    const float* z   = (const float*)d_in[0];
    const float* emb = (const float*)d_in[1];
    float* out = (float*)d_out;

    unsigned char* emb8 = (unsigned char*)d_ws;              // 256 KB
    float*    e_sqs = (float*)((char*)d_ws + 262144);        // 4 KB
    unsigned* sidx  = (unsigned*)((char*)d_ws + 266240);     // 256 KB
    float*    loss  = out + 16777216;

    hipMemsetAsync(loss, 0, sizeof(float), stream);
    emb_prep<<<KCODES, 64, 0, stream>>>(emb, emb8, e_sqs);
    vq_gemm<<<1024, 256, 0, stream>>>(z, emb8, e_sqs, sidx, loss);
    vq_gather<<<2048, 256, 0, stream>>>(emb, sidx, out);
}